// Round 5
// baseline (124.634 us; speedup 1.0000x reference)
//
#include <hip/hip_runtime.h>
#include <math.h>

#define BATCH 4
#define NPTS 8192
#define TB 256              // threads per block
#define TN 8                // n-points per thread (contiguous)
#define NT (TB * TN)        // 2048 n per block
#define NTILES (NPTS / NT)  // 4
#define MCH 32              // m-chunks -> grid 4*32 x 4 x 2 = 1024 blocks (4/CU, co-resident)
#define MC (NPTS / MCH)     // 256 m per chunk
#define NBLK (NTILES * MCH * BATCH * 2)  // 1024

// ws: unsigned minbits[2][BATCH][NPTS] (256 KB), then unsigned counter[1].
// Both init'd by ONE hipMemsetAsync(0xFF): 0xFFFFFFFF is the atomicMin(uint)
// identity, and the counter starts at -1 (last of NBLK arrivals sees NBLK-2).

__global__ __launch_bounds__(TB, 4) void hd_fused(const float* __restrict__ pred,
                                                  const float* __restrict__ gt,
                                                  unsigned* __restrict__ minbits,
                                                  unsigned* __restrict__ counter,
                                                  float* __restrict__ out) {
    const int tid = threadIdx.x;
    const int ntile = blockIdx.x / MCH;
    const int mc = blockIdx.x % MCH;
    const int b = blockIdx.y;
    const int dir = blockIdx.z;

    const float* X = (dir == 0) ? pred + (size_t)b * NPTS * 3 : gt + (size_t)b * NPTS * 3;
    const float* Y = (dir == 0) ? gt + (size_t)b * NPTS * 3 : pred + (size_t)b * NPTS * 3;

    __shared__ float4 tile[MC];  // (y0, y1, y2, |y|^2) — 4 KB
    for (int i = tid; i < MC; i += TB) {
        int m = mc * MC + i;
        float y0 = Y[3 * m], y1 = Y[3 * m + 1], y2 = Y[3 * m + 2];
        tile[i] = make_float4(y0, y1, y2, y0 * y0 + y1 * y1 + y2 * y2);
    }

    // x-points: contiguous per thread -> 6 coalesced float4 loads (96 B)
    const int nbase = ntile * NT;
    const float4* Xq = (const float4*)(X + (size_t)3 * (nbase + tid * TN));
    float xv[24];
#pragma unroll
    for (int i = 0; i < 6; ++i) ((float4*)xv)[i] = Xq[i];

    float a0[TN], a1[TN], a2[TN], a3[TN], rmin[TN];
#pragma unroll
    for (int k = 0; k < TN; ++k) {
        float x0 = xv[3 * k], x1 = xv[3 * k + 1], x2 = xv[3 * k + 2];
        a0[k] = -2.f * x0;
        a1[k] = -2.f * x1;
        a2[k] = -2.f * x2;
        a3[k] = x0 * x0 + x1 * x1 + x2 * x2;  // added back after the inner loop
        rmin[k] = 3.4e38f;
    }
    __syncthreads();

    // d^2 = |x|^2 + (y^2 - 2 x.y): inner loop is 3 fma + 0.5 min3 per pair
    for (int m = 0; m < MC; m += 4) {
        float4 ya = tile[m];
        float4 yb = tile[m + 1];
        float4 yc = tile[m + 2];
        float4 yd = tile[m + 3];
#pragma unroll
        for (int k = 0; k < TN; ++k) {
            float ea = fmaf(a0[k], ya.x, ya.w);
            ea = fmaf(a1[k], ya.y, ea);
            ea = fmaf(a2[k], ya.z, ea);
            float eb = fmaf(a0[k], yb.x, yb.w);
            eb = fmaf(a1[k], yb.y, eb);
            eb = fmaf(a2[k], yb.z, eb);
            rmin[k] = fminf(fminf(ea, eb), rmin[k]);  // v_min3_f32
            float ec = fmaf(a0[k], yc.x, yc.w);
            ec = fmaf(a1[k], yc.y, ec);
            ec = fmaf(a2[k], yc.z, ec);
            float ed = fmaf(a0[k], yd.x, yd.w);
            ed = fmaf(a1[k], yd.y, ed);
            ed = fmaf(a2[k], yd.z, ed);
            rmin[k] = fminf(fminf(ec, ed), rmin[k]);  // v_min3_f32
        }
    }

    unsigned* mb = minbits + ((size_t)(dir * BATCH + b)) * NPTS + nbase + tid * TN;
#pragma unroll
    for (int k = 0; k < TN; ++k) {
        float v = fmaxf(a3[k] + rmin[k], 0.f);  // add back |x|^2, clamp cancellation
        atomicMin(&mb[k], __float_as_uint(v));  // device-scope -> LLC
    }

    // ---- arrival: NO per-block fence. __syncthreads() drains vmcnt(0), so all
    // this block's LLC atomicMins are complete before the counter add issues.
    __syncthreads();
    __shared__ int is_last;
    if (tid == 0) {
        unsigned old = atomicAdd(counter, 1u);
        is_last = (old == (unsigned)(NBLK - 2));  // counter started at 0xFFFFFFFF
    }
    __syncthreads();
    if (!is_last) return;

    __threadfence();  // acquire once: invalidate L1/L2 so plain loads see LLC

    // wave w reduces batch w (both directions) with coalesced uint4 loads
    const int wave = tid >> 6, lane = tid & 63;
    const uint4* q0 = (const uint4*)(minbits + (size_t)wave * NPTS);
    const uint4* q1 = (const uint4*)(minbits + (size_t)(BATCH + wave) * NPTS);
    unsigned vmax = 0u;
#pragma unroll 4
    for (int j = 0; j < NPTS / 4 / 64; ++j) {  // 32 iters
        uint4 u = q0[lane + 64 * j];
        uint4 v = q1[lane + 64 * j];
        unsigned a = max(max(u.x, u.y), max(u.z, u.w));
        unsigned c = max(max(v.x, v.y), max(v.z, v.w));
        vmax = max(vmax, max(a, c));
    }
#pragma unroll
    for (int off = 32; off > 0; off >>= 1) {
        unsigned o = (unsigned)__shfl_down((int)vmax, off, 64);
        vmax = max(vmax, o);
    }
    if (lane == 0) out[wave] = sqrtf(__uint_as_float(vmax));
}

extern "C" void kernel_launch(void* const* d_in, const int* in_sizes, int n_in,
                              void* d_out, int out_size, void* d_ws, size_t ws_size,
                              hipStream_t stream) {
    const float* pred = (const float*)d_in[0];  // [B, N, 3]
    const float* gt = (const float*)d_in[1];    // [B, M, 3]
    unsigned* minbits = (unsigned*)d_ws;
    unsigned* counter = minbits + 2 * BATCH * NPTS;

    (void)hipMemsetAsync(minbits, 0xFF,
                         ((size_t)2 * BATCH * NPTS + 1) * sizeof(unsigned), stream);
    hd_fused<<<dim3(NTILES * MCH, BATCH, 2), TB, 0, stream>>>(pred, gt, minbits, counter,
                                                              (float*)d_out);
}

// Round 6
// 98.082 us; speedup vs baseline: 1.2707x; 1.2707x over previous
//
#include <hip/hip_runtime.h>
#include <math.h>

#define BATCH 4
#define NPTS 8192
#define TB 256              // threads per block
#define TN 8                // n-points per thread (strided: k*TB+tid)
#define NT (TB * TN)        // 2048 n per block
#define NTILES (NPTS / NT)  // 4
#define MCH 64              // m-chunks -> grid 4*64 x 4 x 2 = 2048 blocks
#define MC (NPTS / MCH)     // 128 m per chunk

// ws: unsigned minbits[2][BATCH][NPTS] (256 KB), memset to 0xFF (atomicMin identity)

#define COMPUTE4(q0, q1, q2, q3)                                              \
    _Pragma("unroll") for (int k = 0; k < TN; ++k) {                          \
        float ea = fmaf(a0[k], q0.x, q0.w);                                   \
        ea = fmaf(a1[k], q0.y, ea);                                           \
        ea = fmaf(a2[k], q0.z, ea);                                           \
        float eb = fmaf(a0[k], q1.x, q1.w);                                   \
        eb = fmaf(a1[k], q1.y, eb);                                           \
        eb = fmaf(a2[k], q1.z, eb);                                           \
        rmin[k] = fminf(fminf(ea, eb), rmin[k]);  /* v_min3_f32 */            \
        float ec = fmaf(a0[k], q2.x, q2.w);                                   \
        ec = fmaf(a1[k], q2.y, ec);                                           \
        ec = fmaf(a2[k], q2.z, ec);                                           \
        float ed = fmaf(a0[k], q3.x, q3.w);                                   \
        ed = fmaf(a1[k], q3.y, ed);                                           \
        ed = fmaf(a2[k], q3.z, ed);                                           \
        rmin[k] = fminf(fminf(ec, ed), rmin[k]);  /* v_min3_f32 */            \
    }

// d^2 = |x|^2 + (y^2 - 2 x.y): inner loop 3 fma + 0.5 min3 per pair.
// Mov-free ping-pong: compute(A); reload A from tile[m+8..]; compute(B);
// reload B — every ds_read_b128 gets a ~112-VALU window before first use.
__global__ __launch_bounds__(TB) void hd_partial(const float* __restrict__ pred,
                                                 const float* __restrict__ gt,
                                                 unsigned* __restrict__ minbits) {
    const int tid = threadIdx.x;
    const int ntile = blockIdx.x / MCH;
    const int mc = blockIdx.x % MCH;
    const int b = blockIdx.y;
    const int dir = blockIdx.z;

    const float* X = (dir == 0) ? pred + (size_t)b * NPTS * 3 : gt + (size_t)b * NPTS * 3;
    const float* Y = (dir == 0) ? gt + (size_t)b * NPTS * 3 : pred + (size_t)b * NPTS * 3;

    __shared__ float4 tile[MC];  // (y0, y1, y2, |y|^2) — 2 KB
    if (tid < MC) {
        int m = mc * MC + tid;
        float y0 = Y[3 * m], y1 = Y[3 * m + 1], y2 = Y[3 * m + 2];
        tile[tid] = make_float4(y0, y1, y2, y0 * y0 + y1 * y1 + y2 * y2);
    }

    float a0[TN], a1[TN], a2[TN], a3[TN], rmin[TN];
    const int nbase = ntile * NT;
#pragma unroll
    for (int k = 0; k < TN; ++k) {
        int n = nbase + k * TB + tid;
        float x0 = X[3 * n], x1 = X[3 * n + 1], x2 = X[3 * n + 2];
        a0[k] = -2.f * x0;
        a1[k] = -2.f * x1;
        a2[k] = -2.f * x2;
        a3[k] = x0 * x0 + x1 * x1 + x2 * x2;  // added back after the inner loop
        rmin[k] = 3.4e38f;
    }
    __syncthreads();

    float4 A0 = tile[0], A1 = tile[1], A2 = tile[2], A3 = tile[3];
    float4 B0 = tile[4], B1 = tile[5], B2 = tile[6], B3 = tile[7];
    for (int m = 0; m < MC - 8; m += 8) {
        COMPUTE4(A0, A1, A2, A3)                                       // m..m+3
        A0 = tile[m + 8]; A1 = tile[m + 9]; A2 = tile[m + 10]; A3 = tile[m + 11];
        COMPUTE4(B0, B1, B2, B3)                                       // m+4..m+7
        B0 = tile[m + 12]; B1 = tile[m + 13]; B2 = tile[m + 14]; B3 = tile[m + 15];
    }
    COMPUTE4(A0, A1, A2, A3)  // MC-8..MC-5
    COMPUTE4(B0, B1, B2, B3)  // MC-4..MC-1

    // Coalesced atomic layout (wave spans 256 contiguous bytes per instruction)
    unsigned* mb = minbits + ((size_t)(dir * BATCH + b)) * NPTS + nbase;
#pragma unroll
    for (int k = 0; k < TN; ++k) {
        float v = fmaxf(a3[k] + rmin[k], 0.f);  // add back |x|^2, clamp cancellation
        atomicMin(&mb[k * TB + tid], __float_as_uint(v));
    }
}

// One block per batch: max over both directions and all n, then sqrt -> out.
__global__ __launch_bounds__(256) void hd_reduce(const unsigned* __restrict__ minbits,
                                                 float* __restrict__ out) {
    const int tid = threadIdx.x;
    const int b = blockIdx.x;
    const uint4* p0 = (const uint4*)(minbits + (size_t)b * NPTS);            // dir 0
    const uint4* p1 = (const uint4*)(minbits + (size_t)(BATCH + b) * NPTS);  // dir 1
    unsigned vmax = 0u;
    for (int i = tid; i < NPTS / 4; i += 256) {
        uint4 u = p0[i];
        uint4 v = p1[i];
        unsigned a = max(max(u.x, u.y), max(u.z, u.w));
        unsigned c = max(max(v.x, v.y), max(v.z, v.w));
        vmax = max(vmax, max(a, c));
    }
    __shared__ unsigned sm[256];
    sm[tid] = vmax;
    __syncthreads();
    for (int s = 128; s > 0; s >>= 1) {
        if (tid < s) sm[tid] = max(sm[tid], sm[tid + s]);
        __syncthreads();
    }
    if (tid == 0) out[b] = sqrtf(__uint_as_float(sm[0]));
}

extern "C" void kernel_launch(void* const* d_in, const int* in_sizes, int n_in,
                              void* d_out, int out_size, void* d_ws, size_t ws_size,
                              hipStream_t stream) {
    const float* pred = (const float*)d_in[0];  // [B, N, 3]
    const float* gt = (const float*)d_in[1];    // [B, M, 3]
    unsigned* minbits = (unsigned*)d_ws;

    (void)hipMemsetAsync(minbits, 0xFF, (size_t)2 * BATCH * NPTS * sizeof(unsigned),
                         stream);
    hd_partial<<<dim3(NTILES * MCH, BATCH, 2), TB, 0, stream>>>(pred, gt, minbits);
    hd_reduce<<<BATCH, 256, 0, stream>>>(minbits, (float*)d_out);
}

// Round 7
// 92.613 us; speedup vs baseline: 1.3457x; 1.0591x over previous
//
#include <hip/hip_runtime.h>
#include <math.h>

#define BATCH 4
#define NPTS 8192
#define TB 256
#define XSPAN 512              // x-points per block = 32 tiles of 16
#define NA 8                   // x-tiles per wave (4 waves x 8 x 16 = 512)
#define MC 1024                // y-points per block pass = 64 tiles
#define XBLKS (NPTS / XSPAN)   // 16
#define YBLKS (NPTS / MC)      // 8

typedef _Float16 f16x8 __attribute__((ext_vector_type(8)));
typedef float f32x4 __attribute__((ext_vector_type(4)));

// ws: unsigned minbits[2][BATCH][NPTS] (256 KB), memset 0xFF (atomicMin identity)
//
// d^2(x,y) = x^2 + y^2 - 2x.y computed EXACTLY-ish in ONE mfma_f32_16x16x32_f16:
// split x_c = xh_c + xl_c (f16 Dekker split), y likewise, x^2/y^2 split too.
// K-slot pairing (A = y-side, B = x-side, D[row=y][col=x]):
//  k0..2 : A=-2yh_c        B=xh_c     (hh)
//  k3..5 : A=-2yh_c        B=xl_c     (hl)
//  k6..8 : A=-2yl_c        B=xh_c     (lh)
//  k9..11: A=-2yl_c        B=xl_c     (ll)
//  k12,13: A=y2h,y2l       B=1        (+y^2)
//  k14,15: A=1,1           B=x2h,x2l  (+x^2)
// Residual error ~2^-22 relative => ~1e-4 absolute on d^2.

__global__ __launch_bounds__(TB) void hd_mfma(const float* __restrict__ pred,
                                              const float* __restrict__ gt,
                                              unsigned* __restrict__ minbits) {
    const int tid = threadIdx.x;
    const int xblk = blockIdx.x % XBLKS;
    const int yblk = blockIdx.x / XBLKS;
    const int b = blockIdx.y;
    const int dir = blockIdx.z;

    const float* X = (dir == 0) ? pred + (size_t)b * NPTS * 3 : gt + (size_t)b * NPTS * 3;
    const float* Y = (dir == 0) ? gt + (size_t)b * NPTS * 3 : pred + (size_t)b * NPTS * 3;

    // [0,16384) halves: phase1 x B-frags (32*256h) then phase2 y A-frags (64*256h)
    // [16384,16640): persistent zero block (512 B) for lanes 32..63 (K-quads 2,3)
    __shared__ __align__(16) _Float16 smem[16384 + 256];
    smem[16384 + tid] = (_Float16)0.f;

    // ---- phase 1: x-side B-frags. B[k][n=lane&15], k-group = lane>>4 (0,1) ----
    const int xbase = xblk * XSPAN;
    for (int pl = tid; pl < XSPAN; pl += TB) {
        int p = xbase + pl;
        float x0 = X[3 * p], x1 = X[3 * p + 1], x2c = X[3 * p + 2];
        _Float16 h0 = (_Float16)x0, h1 = (_Float16)x1, h2 = (_Float16)x2c;
        _Float16 l0 = (_Float16)(x0 - (float)h0);
        _Float16 l1 = (_Float16)(x1 - (float)h1);
        _Float16 l2 = (_Float16)(x2c - (float)h2);
        float xsq = fmaf(x0, x0, fmaf(x1, x1, x2c * x2c));
        _Float16 sh = (_Float16)xsq;
        _Float16 sl = (_Float16)(xsq - (float)sh);
        int t = pl >> 4, j = pl & 15;
        f16x8 g0 = {h0, h1, h2, l0, l1, l2, h0, h1};                      // k0..7
        f16x8 g1 = {h2, l0, l1, l2, (_Float16)1.f, (_Float16)1.f, sh, sl};// k8..15
        *(f16x8*)&smem[t * 256 + j * 8] = g0;
        *(f16x8*)&smem[t * 256 + 128 + j * 8] = g1;
    }
    __syncthreads();

    const int wave = tid >> 6, lane = tid & 63;
    f16x8 bfrag[NA];
    if (lane < 32) {
#pragma unroll
        for (int i = 0; i < NA; ++i)
            bfrag[i] = *(f16x8*)&smem[(wave * NA + i) * 256 + lane * 8];
    } else {
#pragma unroll
        for (int i = 0; i < NA; ++i) bfrag[i] = (f16x8)0;  // K-quads 2,3 are zero
    }
    __syncthreads();  // x-frag reads done before y overwrites

    // ---- phase 2: y-side A-frags. A[m=lane&15][k], k-group = lane>>4 ----
    const int ybase = yblk * MC;
    for (int pl = tid; pl < MC; pl += TB) {
        int p = ybase + pl;
        float y0 = Y[3 * p], y1 = Y[3 * p + 1], y2c = Y[3 * p + 2];
        _Float16 h0 = (_Float16)y0, h1 = (_Float16)y1, h2 = (_Float16)y2c;
        _Float16 l0 = (_Float16)(y0 - (float)h0);
        _Float16 l1 = (_Float16)(y1 - (float)h1);
        _Float16 l2 = (_Float16)(y2c - (float)h2);
        float ysq = fmaf(y0, y0, fmaf(y1, y1, y2c * y2c));
        _Float16 sh = (_Float16)ysq;
        _Float16 sl = (_Float16)(ysq - (float)sh);
        const _Float16 n2 = (_Float16)(-2.f);
        _Float16 a0 = n2 * h0, a1 = n2 * h1, a2 = n2 * h2;  // exact (exp shift)
        _Float16 c0 = n2 * l0, c1 = n2 * l1, c2 = n2 * l2;
        int u = pl >> 4, j = pl & 15;
        f16x8 g0 = {a0, a1, a2, a0, a1, a2, c0, c1};                        // k0..7
        f16x8 g1 = {c2, c0, c1, c2, sh, sl, (_Float16)1.f, (_Float16)1.f};  // k8..15
        *(f16x8*)&smem[u * 256 + j * 8] = g0;
        *(f16x8*)&smem[u * 256 + 128 + j * 8] = g1;
    }
    __syncthreads();

    // ---- m-loop: 64 y-tiles, NA MFMAs each; min over rows (=y) per lane ----
    float rmin[NA];
#pragma unroll
    for (int i = 0; i < NA; ++i) rmin[i] = 3.0e38f;

    int aoff = (lane < 32) ? lane * 8 : 16384 + (lane - 32) * 8;  // branchless mask
    const int astep = (lane < 32) ? 256 : 0;
    const f32x4 zc = {0.f, 0.f, 0.f, 0.f};
    for (int u = 0; u < MC / 16; ++u) {
        f16x8 afrag = *(f16x8*)&smem[aoff];
        aoff += astep;
#pragma unroll
        for (int i = 0; i < NA; ++i) {
            f32x4 d = __builtin_amdgcn_mfma_f32_16x16x32_f16(afrag, bfrag[i], zc, 0, 0, 0);
            float t1 = fminf(fminf(d.x, d.y), d.z);      // v_min3
            rmin[i] = fminf(fminf(t1, d.w), rmin[i]);    // v_min3
        }
    }

    // ---- epilogue: cross-quad min (rows live in quads), then atomicMin ----
    unsigned* mb = minbits + ((size_t)(dir * BATCH + b)) * NPTS + xbase;
#pragma unroll
    for (int i = 0; i < NA; ++i) {
        float v = rmin[i];
        v = fminf(v, __shfl_xor(v, 16, 64));
        v = fminf(v, __shfl_xor(v, 32, 64));
        if (lane < 16) {
            v = fmaxf(v, 0.f);  // clamp tiny negative d^2 before uint-bit compare
            atomicMin(&mb[(wave * NA + i) * 16 + lane], __float_as_uint(v));
        }
    }
}

// One block per batch: max over both directions and all n, then sqrt -> out.
__global__ __launch_bounds__(256) void hd_reduce(const unsigned* __restrict__ minbits,
                                                 float* __restrict__ out) {
    const int tid = threadIdx.x;
    const int b = blockIdx.x;
    const uint4* p0 = (const uint4*)(minbits + (size_t)b * NPTS);
    const uint4* p1 = (const uint4*)(minbits + (size_t)(BATCH + b) * NPTS);
    unsigned vmax = 0u;
    for (int i = tid; i < NPTS / 4; i += 256) {
        uint4 u = p0[i];
        uint4 v = p1[i];
        unsigned a = max(max(u.x, u.y), max(u.z, u.w));
        unsigned c = max(max(v.x, v.y), max(v.z, v.w));
        vmax = max(vmax, max(a, c));
    }
    __shared__ unsigned sm[256];
    sm[tid] = vmax;
    __syncthreads();
    for (int s = 128; s > 0; s >>= 1) {
        if (tid < s) sm[tid] = max(sm[tid], sm[tid + s]);
        __syncthreads();
    }
    if (tid == 0) out[b] = sqrtf(__uint_as_float(sm[0]));
}

extern "C" void kernel_launch(void* const* d_in, const int* in_sizes, int n_in,
                              void* d_out, int out_size, void* d_ws, size_t ws_size,
                              hipStream_t stream) {
    const float* pred = (const float*)d_in[0];  // [B, N, 3]
    const float* gt = (const float*)d_in[1];    // [B, M, 3]
    unsigned* minbits = (unsigned*)d_ws;

    (void)hipMemsetAsync(minbits, 0xFF, (size_t)2 * BATCH * NPTS * sizeof(unsigned),
                         stream);
    hd_mfma<<<dim3(XBLKS * YBLKS, BATCH, 2), TB, 0, stream>>>(pred, gt, minbits);
    hd_reduce<<<BATCH, 256, 0, stream>>>(minbits, (float*)d_out);
}

// Round 8
// 85.099 us; speedup vs baseline: 1.4646x; 1.0883x over previous
//
#include <hip/hip_runtime.h>
#include <math.h>

#define BATCH 4
#define NPTS 8192
#define TB 256
#define NB 2                  // B-frags (32 x-cols each) per wave
#define XW (NB * 32)          // 64 x per wave
#define XSPAN (4 * XW)        // 256 x per block
#define XBLKS (NPTS / XSPAN)  // 32
#define YSPAN 1024            // y per block
#define YBLKS (NPTS / YSPAN)  // 8
#define YTILES (YSPAN / 32)   // 32

typedef _Float16 f16x8 __attribute__((ext_vector_type(8)));
typedef float f32x16 __attribute__((ext_vector_type(16)));

// ws: unsigned minbits[2][BATCH][NPTS] (256 KB), memset 0xFF (atomicMin identity)
//
// d^2 = x^2 + y^2 - 2 x.y in ONE mfma_f32_32x32x16_f16 (K=16, zero waste).
// Dekker f16 splits: y=yh+yl, x=xh+xl, y^2=sh+sl, x^2 likewise. K-slots:
//  k0..2: -2yh*xh  k3..5: -2yh*xl  k6..8: -2yl*xh  k9..11: -2yl*xl
//  k12,13: (y2h,y2l)*1     k14,15: 1*(x2h,x2l)
// A[m=lane&31][k=(lane>>5)*8+j]; B[k][n=lane&31] mirrored; C: col=lane&31,
// rows partition over (reg, lane>>5) -> per-lane 16-reg min + shfl_xor(32).

__device__ __forceinline__ float tree17(f32x16 d, float r) {
    float v0 = fminf(fminf(d[0], d[1]), d[2]);
    float v1 = fminf(fminf(d[3], d[4]), d[5]);
    float v2 = fminf(fminf(d[6], d[7]), d[8]);
    float v3 = fminf(fminf(d[9], d[10]), d[11]);
    float v4 = fminf(fminf(d[12], d[13]), d[14]);
    float w0 = fminf(fminf(v0, v1), v2);
    float w1 = fminf(fminf(v3, v4), d[15]);
    return fminf(fminf(w0, w1), r);  // 8x v_min3_f32 total
}

__global__ __launch_bounds__(TB) void hd_mfma(const float* __restrict__ pred,
                                              const float* __restrict__ gt,
                                              unsigned* __restrict__ minbits) {
    const int tid = threadIdx.x;
    const int xblk = blockIdx.x % XBLKS;
    const int yblk = blockIdx.x / XBLKS;
    const int b = blockIdx.y;
    const int dir = blockIdx.z;

    const float* X = (dir == 0) ? pred + (size_t)b * NPTS * 3 : gt + (size_t)b * NPTS * 3;
    const float* Y = (dir == 0) ? gt + (size_t)b * NPTS * 3 : pred + (size_t)b * NPTS * 3;

    __shared__ __align__(16) _Float16 As[YSPAN * 16];  // 32 KB: 16 halves per y-point

    // ---- stage A-frags (y-side) into LDS: 4 points per thread ----
    const int ybase = yblk * YSPAN;
    for (int p = tid; p < YSPAN; p += TB) {
        int gp = ybase + p;
        float y0 = Y[3 * gp], y1 = Y[3 * gp + 1], y2 = Y[3 * gp + 2];
        _Float16 h0 = (_Float16)y0, h1 = (_Float16)y1, h2 = (_Float16)y2;
        _Float16 l0 = (_Float16)(y0 - (float)h0);
        _Float16 l1 = (_Float16)(y1 - (float)h1);
        _Float16 l2 = (_Float16)(y2 - (float)h2);
        float ys = fmaf(y0, y0, fmaf(y1, y1, y2 * y2));
        _Float16 sh = (_Float16)ys, sl = (_Float16)(ys - (float)sh);
        const _Float16 n2 = (_Float16)(-2.f);
        _Float16 A0 = n2 * h0, A1 = n2 * h1, A2 = n2 * h2;
        _Float16 C0 = n2 * l0, C1 = n2 * l1, C2 = n2 * l2;
        f16x8 g0 = {A0, A1, A2, A0, A1, A2, C0, C1};                        // k0..7
        f16x8 g1 = {C2, C0, C1, C2, sh, sl, (_Float16)1.f, (_Float16)1.f};  // k8..15
        *(f16x8*)&As[p * 16] = g0;
        *(f16x8*)&As[p * 16 + 8] = g1;
    }

    // ---- B-frags (x-side) straight into registers, no LDS phase ----
    const int wave = tid >> 6, lane = tid & 63, half = lane >> 5, ln = lane & 31;
    const int xw = xblk * XSPAN + wave * XW;
    f16x8 bf[NB];
#pragma unroll
    for (int i = 0; i < NB; ++i) {
        int px = xw + i * 32 + ln;
        float x0 = X[3 * px], x1 = X[3 * px + 1], x2 = X[3 * px + 2];
        _Float16 h0 = (_Float16)x0, h1 = (_Float16)x1, h2 = (_Float16)x2;
        _Float16 l0 = (_Float16)(x0 - (float)h0);
        _Float16 l1 = (_Float16)(x1 - (float)h1);
        _Float16 l2 = (_Float16)(x2 - (float)h2);
        float xs = fmaf(x0, x0, fmaf(x1, x1, x2 * x2));
        _Float16 sh = (_Float16)xs, sl = (_Float16)(xs - (float)sh);
        f16x8 g0 = {h0, h1, h2, l0, l1, l2, h0, h1};                        // k0..7
        f16x8 g1 = {h2, l0, l1, l2, (_Float16)1.f, (_Float16)1.f, sh, sl};  // k8..15
        bf[i] = half ? g1 : g0;
    }
    __syncthreads();

    const f32x16 zc = {0.f, 0.f, 0.f, 0.f, 0.f, 0.f, 0.f, 0.f,
                       0.f, 0.f, 0.f, 0.f, 0.f, 0.f, 0.f, 0.f};
    float rmin[NB];
#pragma unroll
    for (int i = 0; i < NB; ++i) rmin[i] = 3.0e38f;

    int aoff = ln * 16 + half * 8;  // halves index into As
    for (int u = 0; u < YTILES; ++u) {
        f16x8 af = *(f16x8*)&As[aoff];  // ds_read_b128, balanced banks
        aoff += 512;
#pragma unroll
        for (int i = 0; i < NB; ++i) {
            f32x16 d = __builtin_amdgcn_mfma_f32_32x32x16_f16(af, bf[i], zc, 0, 0, 0);
            rmin[i] = tree17(d, rmin[i]);
        }
    }

    // ---- epilogue: merge lane-halves (rows), coalesced atomicMin per col ----
    unsigned* mb = minbits + ((size_t)(dir * BATCH + b)) * NPTS;
#pragma unroll
    for (int i = 0; i < NB; ++i) {
        float v = fminf(rmin[i], __shfl_xor(rmin[i], 32, 64));
        if (lane < 32) {
            v = fmaxf(v, 0.f);  // clamp tiny negative d^2 before uint-bit compare
            atomicMin(&mb[xw + i * 32 + ln], __float_as_uint(v));
        }
    }
}

// One block per batch: max over both directions and all n, then sqrt -> out.
__global__ __launch_bounds__(256) void hd_reduce(const unsigned* __restrict__ minbits,
                                                 float* __restrict__ out) {
    const int tid = threadIdx.x;
    const int b = blockIdx.x;
    const uint4* p0 = (const uint4*)(minbits + (size_t)b * NPTS);
    const uint4* p1 = (const uint4*)(minbits + (size_t)(BATCH + b) * NPTS);
    unsigned vmax = 0u;
    for (int i = tid; i < NPTS / 4; i += 256) {
        uint4 u = p0[i];
        uint4 v = p1[i];
        unsigned a = max(max(u.x, u.y), max(u.z, u.w));
        unsigned c = max(max(v.x, v.y), max(v.z, v.w));
        vmax = max(vmax, max(a, c));
    }
    __shared__ unsigned sm[256];
    sm[tid] = vmax;
    __syncthreads();
    for (int s = 128; s > 0; s >>= 1) {
        if (tid < s) sm[tid] = max(sm[tid], sm[tid + s]);
        __syncthreads();
    }
    if (tid == 0) out[b] = sqrtf(__uint_as_float(sm[0]));
}

extern "C" void kernel_launch(void* const* d_in, const int* in_sizes, int n_in,
                              void* d_out, int out_size, void* d_ws, size_t ws_size,
                              hipStream_t stream) {
    const float* pred = (const float*)d_in[0];  // [B, N, 3]
    const float* gt = (const float*)d_in[1];    // [B, M, 3]
    unsigned* minbits = (unsigned*)d_ws;

    (void)hipMemsetAsync(minbits, 0xFF, (size_t)2 * BATCH * NPTS * sizeof(unsigned),
                         stream);
    hd_mfma<<<dim3(XBLKS * YBLKS, BATCH, 2), TB, 0, stream>>>(pred, gt, minbits);
    hd_reduce<<<BATCH, 256, 0, stream>>>(minbits, (float*)d_out);
}

// Round 9
// 78.696 us; speedup vs baseline: 1.5837x; 1.0814x over previous
//
#include <hip/hip_runtime.h>
#include <math.h>

#define BATCH 4
#define NPTS 8192
#define TB 256
#define NB 2                  // B-frags (32 x-cols each) per wave
#define XW (NB * 32)          // 64 x per wave
#define XSPAN (4 * XW)        // 256 x per block
#define XBLKS (NPTS / XSPAN)  // 32
#define YSPAN 1024            // y per block
#define YBLKS (NPTS / YSPAN)  // 8
#define YTILES (YSPAN / 32)   // 32

typedef _Float16 f16x8 __attribute__((ext_vector_type(8)));
typedef float f32x16 __attribute__((ext_vector_type(16)));

// ws: unsigned minbits[2][BATCH][NPTS] (256 KB), memset 0xFF (atomicMin identity)
//
// d^2 = x^2 + y^2 - 2 x.y in ONE mfma_f32_32x32x16_f16 (K=16, zero waste).
// Dekker f16 splits: y=yh+yl, x=xh+xl, y^2=sh+sl, x^2 likewise. K-slots:
//  k0..2: -2yh*xh  k3..5: -2yh*xl  k6..8: -2yl*xh  k9..11: -2yl*xl
//  k12,13: (y2h,y2l)*1     k14,15: 1*(x2h,x2l)
// A[m=lane&31][k=(lane>>5)*8+j]; B[k][n=lane&31] mirrored; C: col=lane&31,
// rows partition over (reg, lane>>5) -> per-lane 16-reg min + shfl_xor(32).
//
// MFMA emitted via inline asm with "v" constraints: on gfx950's unified
// register file C/D live in ArchVGPRs, so the min-tree reads D directly —
// no v_accvgpr_read/write churn (R7 counters showed ~14 extra VALU/MFMA
// with the intrinsic). s_nops cover the MFMA->VALU D-read hazard.

__device__ __forceinline__ float tree17(f32x16 d, float r) {
    float v0 = fminf(fminf(d[0], d[1]), d[2]);
    float v1 = fminf(fminf(d[3], d[4]), d[5]);
    float v2 = fminf(fminf(d[6], d[7]), d[8]);
    float v3 = fminf(fminf(d[9], d[10]), d[11]);
    float v4 = fminf(fminf(d[12], d[13]), d[14]);
    float w0 = fminf(fminf(v0, v1), v2);
    float w1 = fminf(fminf(v3, v4), d[15]);
    return fminf(fminf(w0, w1), r);  // 8x v_min3_f32 total
}

__global__ __launch_bounds__(TB) void hd_mfma(const float* __restrict__ pred,
                                              const float* __restrict__ gt,
                                              unsigned* __restrict__ minbits) {
    const int tid = threadIdx.x;
    const int xblk = blockIdx.x % XBLKS;
    const int yblk = blockIdx.x / XBLKS;
    const int b = blockIdx.y;
    const int dir = blockIdx.z;

    const float* X = (dir == 0) ? pred + (size_t)b * NPTS * 3 : gt + (size_t)b * NPTS * 3;
    const float* Y = (dir == 0) ? gt + (size_t)b * NPTS * 3 : pred + (size_t)b * NPTS * 3;

    __shared__ __align__(16) _Float16 As[YSPAN * 16];  // 32 KB: 16 halves per y-point

    // ---- stage A-frags (y-side) into LDS: 4 points per thread ----
    const int ybase = yblk * YSPAN;
    for (int p = tid; p < YSPAN; p += TB) {
        int gp = ybase + p;
        float y0 = Y[3 * gp], y1 = Y[3 * gp + 1], y2 = Y[3 * gp + 2];
        _Float16 h0 = (_Float16)y0, h1 = (_Float16)y1, h2 = (_Float16)y2;
        _Float16 l0 = (_Float16)(y0 - (float)h0);
        _Float16 l1 = (_Float16)(y1 - (float)h1);
        _Float16 l2 = (_Float16)(y2 - (float)h2);
        float ys = fmaf(y0, y0, fmaf(y1, y1, y2 * y2));
        _Float16 sh = (_Float16)ys, sl = (_Float16)(ys - (float)sh);
        const _Float16 n2 = (_Float16)(-2.f);
        _Float16 A0 = n2 * h0, A1 = n2 * h1, A2 = n2 * h2;
        _Float16 C0 = n2 * l0, C1 = n2 * l1, C2 = n2 * l2;
        f16x8 g0 = {A0, A1, A2, A0, A1, A2, C0, C1};                        // k0..7
        f16x8 g1 = {C2, C0, C1, C2, sh, sl, (_Float16)1.f, (_Float16)1.f};  // k8..15
        *(f16x8*)&As[p * 16] = g0;
        *(f16x8*)&As[p * 16 + 8] = g1;
    }

    // ---- B-frags (x-side) straight into registers, no LDS phase ----
    const int wave = tid >> 6, lane = tid & 63, half = lane >> 5, ln = lane & 31;
    const int xw = xblk * XSPAN + wave * XW;
    f16x8 bf0, bf1;
    {
        int px = xw + ln;
        float x0 = X[3 * px], x1 = X[3 * px + 1], x2 = X[3 * px + 2];
        _Float16 h0 = (_Float16)x0, h1 = (_Float16)x1, h2 = (_Float16)x2;
        _Float16 l0 = (_Float16)(x0 - (float)h0);
        _Float16 l1 = (_Float16)(x1 - (float)h1);
        _Float16 l2 = (_Float16)(x2 - (float)h2);
        float xs = fmaf(x0, x0, fmaf(x1, x1, x2 * x2));
        _Float16 sh = (_Float16)xs, sl = (_Float16)(xs - (float)sh);
        f16x8 g0 = {h0, h1, h2, l0, l1, l2, h0, h1};                        // k0..7
        f16x8 g1 = {h2, l0, l1, l2, (_Float16)1.f, (_Float16)1.f, sh, sl};  // k8..15
        bf0 = half ? g1 : g0;
    }
    {
        int px = xw + 32 + ln;
        float x0 = X[3 * px], x1 = X[3 * px + 1], x2 = X[3 * px + 2];
        _Float16 h0 = (_Float16)x0, h1 = (_Float16)x1, h2 = (_Float16)x2;
        _Float16 l0 = (_Float16)(x0 - (float)h0);
        _Float16 l1 = (_Float16)(x1 - (float)h1);
        _Float16 l2 = (_Float16)(x2 - (float)h2);
        float xs = fmaf(x0, x0, fmaf(x1, x1, x2 * x2));
        _Float16 sh = (_Float16)xs, sl = (_Float16)(xs - (float)sh);
        f16x8 g0 = {h0, h1, h2, l0, l1, l2, h0, h1};
        f16x8 g1 = {h2, l0, l1, l2, (_Float16)1.f, (_Float16)1.f, sh, sl};
        bf1 = half ? g1 : g0;
    }
    __syncthreads();

    const f32x16 zc = {0.f, 0.f, 0.f, 0.f, 0.f, 0.f, 0.f, 0.f,
                       0.f, 0.f, 0.f, 0.f, 0.f, 0.f, 0.f, 0.f};
    float rmin0 = 3.0e38f, rmin1 = 3.0e38f;

    int aoff = ln * 16 + half * 8;  // halves index into As
    for (int u = 0; u < YTILES; ++u) {
        f16x8 af = *(f16x8*)&As[aoff];  // ds_read_b128 (compiler adds lgkmcnt wait)
        aoff += 512;
        f32x16 d0, d1;
        // s_nop 1: VALU-write -> MFMA-src hazard; trailing 18 cyc of s_nop:
        // MFMA-D -> VALU-read hazard (32x32, worst case), covers both D's.
        asm volatile(
            "s_nop 1\n\t"
            "v_mfma_f32_32x32x16_f16 %0, %2, %3, %5\n\t"
            "v_mfma_f32_32x32x16_f16 %1, %2, %4, %5\n\t"
            "s_nop 7\n\t"
            "s_nop 7\n\t"
            "s_nop 1\n\t"
            : "=&v"(d0), "=&v"(d1)
            : "v"(af), "v"(bf0), "v"(bf1), "v"(zc));
        rmin0 = tree17(d0, rmin0);
        rmin1 = tree17(d1, rmin1);
    }

    // ---- epilogue: merge lane-halves (rows), coalesced atomicMin per col ----
    unsigned* mb = minbits + ((size_t)(dir * BATCH + b)) * NPTS;
    {
        float v = fminf(rmin0, __shfl_xor(rmin0, 32, 64));
        if (lane < 32) {
            v = fmaxf(v, 0.f);  // clamp tiny negative d^2 before uint-bit compare
            atomicMin(&mb[xw + ln], __float_as_uint(v));
        }
    }
    {
        float v = fminf(rmin1, __shfl_xor(rmin1, 32, 64));
        if (lane < 32) {
            v = fmaxf(v, 0.f);
            atomicMin(&mb[xw + 32 + ln], __float_as_uint(v));
        }
    }
}

// One block per batch: max over both directions and all n, then sqrt -> out.
__global__ __launch_bounds__(256) void hd_reduce(const unsigned* __restrict__ minbits,
                                                 float* __restrict__ out) {
    const int tid = threadIdx.x;
    const int b = blockIdx.x;
    const uint4* p0 = (const uint4*)(minbits + (size_t)b * NPTS);
    const uint4* p1 = (const uint4*)(minbits + (size_t)(BATCH + b) * NPTS);
    unsigned vmax = 0u;
    for (int i = tid; i < NPTS / 4; i += 256) {
        uint4 u = p0[i];
        uint4 v = p1[i];
        unsigned a = max(max(u.x, u.y), max(u.z, u.w));
        unsigned c = max(max(v.x, v.y), max(v.z, v.w));
        vmax = max(vmax, max(a, c));
    }
    __shared__ unsigned sm[256];
    sm[tid] = vmax;
    __syncthreads();
    for (int s = 128; s > 0; s >>= 1) {
        if (tid < s) sm[tid] = max(sm[tid], sm[tid + s]);
        __syncthreads();
    }
    if (tid == 0) out[b] = sqrtf(__uint_as_float(sm[0]));
}

extern "C" void kernel_launch(void* const* d_in, const int* in_sizes, int n_in,
                              void* d_out, int out_size, void* d_ws, size_t ws_size,
                              hipStream_t stream) {
    const float* pred = (const float*)d_in[0];  // [B, N, 3]
    const float* gt = (const float*)d_in[1];    // [B, M, 3]
    unsigned* minbits = (unsigned*)d_ws;

    (void)hipMemsetAsync(minbits, 0xFF, (size_t)2 * BATCH * NPTS * sizeof(unsigned),
                         stream);
    hd_mfma<<<dim3(XBLKS * YBLKS, BATCH, 2), TB, 0, stream>>>(pred, gt, minbits);
    hd_reduce<<<BATCH, 256, 0, stream>>>(minbits, (float*)d_out);
}